// Round 5
// baseline (532.522 us; speedup 1.0000x reference)
//
#include <hip/hip_runtime.h>

// SimpleRNN: h_{t+1} = tanh(h_t @ H^T + x_t @ U + b); out = h_T @ A^T + c
// T=512 B=2048 IN=28 HID=198 OUT=10, fp32 in/out, fp16 recurrence.
//
// R13: phase-interleave via 2 independent blocks/CU.
// R12 (306us, step 1434cyc) killed bank conflicts (27.3M->538K) with ZERO
// time change -> LDS occupancy not binding. Accounting: LDS burst ~624 +
// VALU ~513 + MFMA ~450 (dep-latency rate) ~= 1587 ~= step: the pipes
// SERIALIZE because all 16 waves are barrier-locked into the same phase.
// Fix: grid=512, BB=4, 8 waves/block, 2 blocks/CU (16 waves/CU = 4/SIMD,
// R9 lesson preserved). Blocks share no barrier -> block A's MFMA/tanh
// overlaps block B's LDS burst.
//
// Layout (diagonal k-half MFMA, BB=4): A rows 0-7 = (b=0..3 x khalf),
// rows 8-15 duplicate (2-way same-address LDS broadcast = free, m136).
//   row m: b=(m&7)>>1, khalf=m&1. B cols 0-7 = 8 j's @ k-lo, 8-15 same @ k-hi.
// C[4q+r][n16]: lane keeps r0 (lo) / r3 (hi), partner (lane^8) supplies
// r1/r2 via ONE full-EXEC row_ror:8 (R10 lesson: no convergent op under
// divergent control). acc init {bias,0,0,bias} -> bias lands exactly once.
// Quads 0-1 own outputs (b = 2q + hi); quads 2-3 are duplicates, writes
// suppressed. 7 compute waves x {4,4,4,4,3,3,3} groups = 25 groups of 8
// cols (>=198; phantom j guarded). Per wave: 4 ds_read_b128 (shared by all
// its groups) + 4*ng MFMAs in ng independent 4-chains.
// K layout: k 0..197 = H, 224..251 = x (tau3 khi slots), gaps zero forever.
// Stager: wave 7 lanes 0-15 (b=lane>>2, kq=lane&3), depth-2 reg pipeline
// (load x[t+3] during t, commit at t+2).

#define T_STEPS 512
#define BATCH   2048
#define IN_DIM  28
#define HID     198
#define OUT_DIM 10
#define BB      4      // batch rows per block
#define NTAU    4      // K-tiles of 64
#define NTHREADS 512   // 8 waves
#define NGMAX   4

typedef __attribute__((ext_vector_type(8))) _Float16 half8;
typedef __attribute__((ext_vector_type(4))) float   floatx4;

__device__ __forceinline__ floatx4 mfma16(half8 a, half8 b, floatx4 c) {
    return __builtin_amdgcn_mfma_f32_16x16x32_f16(a, b, c, 0, 0, 0);
}

// tanh(x) = 1 - 2/(exp(2x)+1); exp2-based, saturates via IEEE inf/0.
__device__ __forceinline__ float fast_tanh(float x) {
    float e = __builtin_amdgcn_exp2f(x * 2.885390081777926357f); // exp(2x)
    float r = __builtin_amdgcn_rcpf(e + 1.0f);
    return __builtin_fmaf(-2.0f, r, 1.0f);
}

// lane <- lane^8 within each 16-lane DPP row. Full-EXEC straight-line only.
__device__ __forceinline__ float ror8(float v) {
    return __builtin_bit_cast(float,
        __builtin_amdgcn_mov_dpp(__builtin_bit_cast(int, v),
                                 0x128 /*row_ror:8*/, 0xf, 0xf, true));
}

__global__ void __launch_bounds__(NTHREADS, 4)
rnn_kernel(const float* __restrict__ x, const float* __restrict__ H,
           const float* __restrict__ U, const float* __restrict__ A,
           const float* __restrict__ bvec, const float* __restrict__ cvec,
           float* __restrict__ out)
{
    // [buf][tau][slot][idx] fp16; slot(b,khalf,kq) = kq*8 + b*2 + khalf.
    // Lane (n16,q) reads b128 at slot q*8 + (n16&7): per 16-lane phase,
    // 8 unique slots (banks 0-31 exactly once) + 8 same-addr duplicates.
    __shared__ __align__(16) _Float16 lds_A[2][NTAU][32][8];   // 4 KB
    __shared__ float lds_h[BB][204];                            // final h

    const int tid  = threadIdx.x;
    const int lane = tid & 63;
    const int wv   = tid >> 6;          // wave id 0..7
    const int n16  = lane & 15;
    const int q    = lane >> 4;         // 0..3
    const int jl   = n16 & 7;
    const int b0   = blockIdx.x * BB;

    // zero-init both buffers (h0 = 0; phantom K slots stay 0 forever)
    {
        _Float16* p0 = &lds_A[0][0][0][0];
        for (int i = tid; i < 2*NTAU*32*8; i += NTHREADS) p0[i] = (_Float16)0.0f;
    }

    const floatx4 zero4 = {0.0f, 0.0f, 0.0f, 0.0f};
    const bool is_cw = (wv < 7);

    const int aslot = q*8 + (n16 & 7);

    // group assignment: waves 0-3 -> 4 groups, waves 4-6 -> 3 groups (25 total)
    const int ng    = (wv < 4) ? 4 : 3;
    const int gbase = (wv < 4) ? 4*wv : 16 + 3*(wv - 4);

    // epilogue ownership (valid on quads 0-1): b = 2q + (n16>>3)
    const int b_lane = (2*q + (n16 >> 3)) & 3;

    // ---- stationary B fragments, biases, epilogue offsets per group ----
    half8 Bf[NGMAX][NTAU];
    float bias[NGMAX];
    int   eoff[NGMAX];      // fp16 offset within one [NTAU][32][8] buffer
    int   jcol[NGMAX];
    if (is_cw) {
        #pragma unroll
        for (int g = 0; g < NGMAX; ++g) {
            const int jbase = (gbase + g) * 8;
            const int j = jbase + jl;
            jcol[g] = j;
            const bool act = (g < ng) && (j < HID);
            bias[g] = act ? bvec[j] : 0.0f;
            // h(b_lane, j): tau=j>>6, slot=((j>>3)&3)*8 + b_lane*2 + ((j>>5)&1)
            eoff[g] = (j >> 6)*256
                    + ((((j >> 3) & 3)*8) + b_lane*2 + ((j >> 5) & 1))*8
                    + (j & 7);
            #pragma unroll
            for (int tau = 0; tau < NTAU; ++tau) {
                half8 f;
                #pragma unroll
                for (int i = 0; i < 8; ++i) {
                    const int k = tau*64 + (n16 >> 3)*32 + q*8 + i;
                    float v = 0.0f;
                    if (act) {
                        if (k < HID)                          v = H[j*HID + k];
                        else if (k >= 224 && k < 224+IN_DIM)  v = U[(k-224)*HID + j];
                    }
                    f[i] = (_Float16)v;
                }
                Bf[g][tau] = f;
            }
        }
    }

    // ---- x stager (wave 7, lanes 0-15): depth-2 register pipeline ----
    // lane = b*4 + kq; x[xi] at k=224+xi -> tau3, slot = kq*8 + b*2 + 1.
    const int sb  = (lane >> 2) & 3;
    const int skq = lane & 3;
    const int sslot = skq*8 + sb*2 + 1;
    const float* xrow_s = x + (size_t)(b0 + sb) * IN_DIM + skq*8;
    const size_t tstride = (size_t)BATCH * IN_DIM;
    floatx4 sA0 = zero4, sA1 = zero4, sB0 = zero4, sB1 = zero4;

    auto issueLd = [&](int tn, floatx4& f0, floatx4& f1) {
        const float* p = xrow_s + (size_t)tn * tstride;
        f0 = *(const floatx4*)p;
        f1 = (skq < 3) ? *(const floatx4*)(p + 4) : zero4;  // IN=28 tail zeroed
    };
    auto commitX = [&](floatx4 f0, floatx4 f1, int buf) {
        half8 ax;
        ax[0] = (_Float16)f0[0]; ax[1] = (_Float16)f0[1];
        ax[2] = (_Float16)f0[2]; ax[3] = (_Float16)f0[3];
        ax[4] = (_Float16)f1[0]; ax[5] = (_Float16)f1[1];
        ax[6] = (_Float16)f1[2]; ax[7] = (_Float16)f1[3];
        *(half8*)&lds_A[buf][3][sslot][0] = ax;
    };

    __syncthreads();   // zero-fill visible before prologue writes

    if (wv == 7 && lane < 16) {
        floatx4 t0, t1;
        issueLd(0, t0, t1);           // x[0]
        issueLd(1, sA0, sA1);         // x[1] -> slot A
        issueLd(2, sB0, sB1);         // x[2] -> slot B
        commitX(t0, t1, 0);           // x[0] into buf 0 (read at step 0)
    }

    auto computeStep = [&](int rb, int wb, bool last) {
        if (!is_cw) return;
        half8 av[NTAU];
        #pragma unroll
        for (int tau = 0; tau < NTAU; ++tau)
            av[tau] = *(const half8*)&lds_A[rb][tau][aslot][0];
        _Float16* wbase = &lds_A[wb][0][0][0];
        #pragma unroll
        for (int g = 0; g < NGMAX; ++g) {
            if (g < ng) {                      // wave-uniform
                floatx4 a = {bias[g], 0.0f, 0.0f, bias[g]};
                #pragma unroll
                for (int tau = 0; tau < NTAU; ++tau)
                    a = mfma16(av[tau], Bf[g][tau], a);
                // lane keeps r0 (lo) / r3 (hi); partner supplies r1/r2.
                const float send = (n16 < 8) ? a[2] : a[1];
                const float recv = ror8(send);           // full-EXEC
                const float s = ((n16 < 8) ? a[0] : a[3]) + recv;
                const float v = fast_tanh(s);
                if (q < 2 && jcol[g] < HID) {            // quads 2-3 are dups
                    wbase[eoff[g]] = (_Float16)v;
                    if (last) lds_h[b_lane][jcol[g]] = v;
                }
            }
        }
    };

    // ================= time loop, 2 steps/iter (static reg slots) =========
    // even step t:  commit slot A (x[t+1]) -> buf1, refill A with x[t+3]
    // odd step t+1: commit slot B (x[t+2]) -> buf0, refill B with x[t+4]
    #pragma unroll 1
    for (int t = 0; t < T_STEPS; t += 2) {
        __syncthreads();
        if (wv == 7 && lane < 16) {
            commitX(sA0, sA1, 1);
            const int tn = (t+3 < T_STEPS) ? (t+3) : (T_STEPS-1);
            issueLd(tn, sA0, sA1);
        }
        computeStep(0, 1, false);

        __syncthreads();
        if (wv == 7 && lane < 16) {
            commitX(sB0, sB1, 0);
            const int tn = (t+4 < T_STEPS) ? (t+4) : (T_STEPS-1);
            issueLd(tn, sB0, sB1);
        }
        computeStep(1, 0, (t + 2) == T_STEPS);
    }

    __syncthreads();

    // ---- output: out[b][o] = sum_k h[b][k]*A[o][k] + c[o] (tiny, scalar) ----
    if (tid < BB * OUT_DIM) {
        const int r = tid / OUT_DIM;
        const int o = tid % OUT_DIM;
        float s = cvec[o];
        for (int k = 0; k < HID; ++k) s += lds_h[r][k] * A[o*HID + k];
        out[(size_t)(b0 + r) * OUT_DIM + o] = s;
    }
}

extern "C" void kernel_launch(void* const* d_in, const int* in_sizes, int n_in,
                              void* d_out, int out_size, void* d_ws, size_t ws_size,
                              hipStream_t stream) {
    const float* x  = (const float*)d_in[0];
    const float* H  = (const float*)d_in[1];
    const float* U  = (const float*)d_in[2];
    const float* A  = (const float*)d_in[3];
    const float* b  = (const float*)d_in[4];
    const float* c  = (const float*)d_in[5];
    float* out = (float*)d_out;

    rnn_kernel<<<dim3(BATCH / BB), dim3(NTHREADS), 0, stream>>>(x, H, U, A, b, c, out);
}